// Round 3
// baseline (154.923 us; speedup 1.0000x reference)
//
#include <hip/hip_runtime.h>

#define NN 2304
#define CC 256
#define HH 8
#define HD 32
#define NYY 48
#define SCALE 0.17677669529663687f

typedef __bf16 bf16_t;
typedef __bf16 bf8v __attribute__((ext_vector_type(8)));
typedef __bf16 bf4v __attribute__((ext_vector_type(4)));
typedef float f4v __attribute__((ext_vector_type(4)));

__device__ __forceinline__ f4v mfma16(bf8v a, bf8v b, f4v c) {
    return __builtin_amdgcn_mfma_f32_16x16x32_bf16(a, b, c, 0, 0, 0);
}

// ---------------------------------------------------------------------------
// Kernel 1 (fused preprocessing):
//   blocks [0,288):   transpose-convert x (256 x 2304 f32) -> xT (2304 x 256 bf16)
//   blocks [288,416): convert Wq|Wk|Wv|Wp (each 256x256 f32) -> Wb bf16 (4x65536)
// ---------------------------------------------------------------------------
__global__ __launch_bounds__(256) void k_pre(
    const float* __restrict__ x, bf16_t* __restrict__ xT,
    const float* __restrict__ Wq, const float* __restrict__ Wk,
    const float* __restrict__ Wv, const float* __restrict__ Wp,
    bf16_t* __restrict__ Wb) {
    const int b = blockIdx.x;
    const int t = threadIdx.x;
    if (b < 288) {
        __shared__ float tile[64][33];
        const int c0 = (b & 7) * 32;
        const int n0 = (b >> 3) * 64;
        const int n = t & 63, cb = t >> 6;
#pragma unroll
        for (int cc = 0; cc < 8; cc++) {
            int c = cc * 4 + cb;
            tile[n][c] = x[(size_t)(c0 + c) * NN + n0 + n];
        }
        __syncthreads();
        const int c = t & 31, nb = t >> 5;
#pragma unroll
        for (int nn = 0; nn < 8; nn++) {
            int n2 = nn * 8 + nb;
            xT[(size_t)(n0 + n2) * CC + c0 + c] = (bf16_t)tile[n2][c];
        }
    } else {
        const int wb = b - 288;
        const int matid = wb >> 5;            // 0..3
        const float* src = (matid == 0) ? Wq : (matid == 1) ? Wk : (matid == 2) ? Wv : Wp;
        const int base = (wb & 31) * 2048 + t * 8;
        float4 a = *(const float4*)(src + base);
        float4 c = *(const float4*)(src + base + 4);
        bf8v o;
        o[0] = (bf16_t)a.x; o[1] = (bf16_t)a.y; o[2] = (bf16_t)a.z; o[3] = (bf16_t)a.w;
        o[4] = (bf16_t)c.x; o[5] = (bf16_t)c.y; o[6] = (bf16_t)c.z; o[7] = (bf16_t)c.w;
        *(bf8v*)(Wb + (size_t)matid * 65536 + base) = o;
    }
}

// ---------------------------------------------------------------------------
// Kernel 2: QKV projection GEMM (M=256 o, N=2304 n, K=256 c), bf16 weights.
// Block: 64 o x 32 n (4 waves, each 16o x 32n).  864 blocks = 13.5 waves/CU.
// ---------------------------------------------------------------------------
__global__ __launch_bounds__(256) void k_proj_qkv(
    const bf16_t* __restrict__ Wb,
    const float* __restrict__ bq, const float* __restrict__ bk,
    const float* __restrict__ bv,
    const bf16_t* __restrict__ xT,
    bf16_t* __restrict__ Qt, bf16_t* __restrict__ Kt, bf16_t* __restrict__ Vd) {
    const int mat = blockIdx.z;
    const bf16_t* W = Wb + (size_t)mat * 65536;
    const float* bias = (mat == 0) ? bq : (mat == 1) ? bk : bv;
    const int n0 = blockIdx.x * 32;
    const int o0 = blockIdx.y * 64;
    const int lane = threadIdx.x & 63;
    const int wave = threadIdx.x >> 6;
    const int l15 = lane & 15;
    const int quad = lane >> 4;
    const int orow = o0 + wave * 16;

    f4v acc0 = {0.f, 0.f, 0.f, 0.f}, acc1 = {0.f, 0.f, 0.f, 0.f};
#pragma unroll
    for (int k0 = 0; k0 < CC; k0 += 32) {
        bf8v af = *(const bf8v*)(W + (size_t)(orow + l15) * CC + k0 + quad * 8);
        bf8v b0 = *(const bf8v*)(xT + (size_t)(n0 + l15) * CC + k0 + quad * 8);
        bf8v b1 = *(const bf8v*)(xT + (size_t)(n0 + 16 + l15) * CC + k0 + quad * 8);
        acc0 = mfma16(af, b0, acc0);
        acc1 = mfma16(af, b1, acc1);
    }

#pragma unroll
    for (int r = 0; r < 4; r++) {
        const int o = orow + quad * 4 + r;
        const float bo = bias[o];
#pragma unroll
        for (int nb = 0; nb < 2; nb++) {
            const int n = n0 + nb * 16 + l15;
            float v = (nb ? acc1[r] : acc0[r]) + bo;
            if (mat == 2) {
                Vd[(size_t)o * NN + n] = (bf16_t)v;
            } else {
                int h = o >> 5, d = o & 31;
                bf16_t* dst = (mat == 0) ? Qt : Kt;
                float vv = (mat == 0) ? v * SCALE : v;
                dst[(size_t)h * NN * HD + (size_t)n * HD + d] = (bf16_t)vv;
            }
        }
    }
}

// ---------------------------------------------------------------------------
// Kernel 3: split-K fused attention, static trip count NITER = (NN/S)/32.
// Grid (288, S). Block = 1 head x 64 q rows. Explicit 1-deep K/V prefetch;
// incremental key (xj,yj) coords; __launch_bounds__(256,8) pins VGPR<=64
// so the 32-waves/CU occupancy is preserved.
// ---------------------------------------------------------------------------
template <int NITER>
__global__ __launch_bounds__(256, 8) void k_attn_split(
    const bf16_t* __restrict__ Qt, const bf16_t* __restrict__ Kt,
    const bf16_t* __restrict__ Vd, const float* __restrict__ emb,
    float* __restrict__ pO, float* __restrict__ pl) {
    __shared__ float lds_emb[40];
    __shared__ bf16_t lds_p[4][16 * 32];
    const int h = blockIdx.x & 7;
    const int qt = blockIdx.x >> 3;
    const int sidx = blockIdx.y;
    const int t = threadIdx.x;
    if (t < 37) lds_emb[t] = (t < 36) ? emb[t * HH + h] : 0.0f;
    __syncthreads();

    const int wave = t >> 6, lane = t & 63;
    const int l15 = lane & 15, quad = lane >> 4;
    const int qg0 = qt * 64 + wave * 16;
    const bf16_t* Qh = Qt + (size_t)h * NN * HD;
    const bf16_t* Kh = Kt + (size_t)h * NN * HD;
    const bf16_t* Vh = Vd + (size_t)h * HD * NN;

    const bf8v aq = *(const bf8v*)(Qh + (size_t)(qg0 + l15) * HD + quad * 8);

    int xi[4], yi[4];
#pragma unroll
    for (int r = 0; r < 4; r++) {
        int qi = qg0 + quad * 4 + r;
        xi[r] = qi / NYY;
        yi[r] = qi - xi[r] * NYY;
    }

    const int k_begin = sidx * (NITER * 32);
    // incremental key coords: kj0 = kb + l15, kj1 = kb + 16 + l15
    int kj0 = k_begin + l15;
    int xj0 = kj0 / NYY, yj0 = kj0 - xj0 * NYY;
    int yj1 = yj0 + 16, xj1 = xj0;
    if (yj1 >= NYY) { yj1 -= NYY; xj1++; }

    f4v o0 = {0.f, 0.f, 0.f, 0.f}, o1 = {0.f, 0.f, 0.f, 0.f};
    const f4v z = {0.f, 0.f, 0.f, 0.f};
    float lsum[4] = {0.f, 0.f, 0.f, 0.f};
    bf16_t* plds = &lds_p[wave][0];

    bf8v kf0 = *(const bf8v*)(Kh + (size_t)(k_begin + l15) * HD + quad * 8);
    bf8v kf1 = *(const bf8v*)(Kh + (size_t)(k_begin + 16 + l15) * HD + quad * 8);
    bf8v vf0 = *(const bf8v*)(Vh + (size_t)l15 * NN + k_begin + quad * 8);
    bf8v vf1 = *(const bf8v*)(Vh + (size_t)(16 + l15) * NN + k_begin + quad * 8);

#pragma unroll 1
    for (int it = 0; it < NITER; ++it) {
        const int kb = k_begin + it * 32;
        // clamped prefetch address (last iter re-loads chunk start, unused)
        const int nkb = (it + 1 < NITER) ? kb + 32 : k_begin;
        bf8v nkf0 = *(const bf8v*)(Kh + (size_t)(nkb + l15) * HD + quad * 8);
        bf8v nkf1 = *(const bf8v*)(Kh + (size_t)(nkb + 16 + l15) * HD + quad * 8);
        bf8v nvf0 = *(const bf8v*)(Vh + (size_t)l15 * NN + nkb + quad * 8);
        bf8v nvf1 = *(const bf8v*)(Vh + (size_t)(16 + l15) * NN + nkb + quad * 8);

        f4v s0 = mfma16(aq, kf0, z);
        f4v s1 = mfma16(aq, kf1, z);
#pragma unroll
        for (int r = 0; r < 4; r++) {
            int dx = xi[r] - xj0; dx = dx < 0 ? -dx : dx;
            int dy = yi[r] - yj0; dy = dy < 0 ? -dy : dy;
            int tok = (dx > 5 || dy > 5) ? 36 : dx * 6 + dy;
            float p = __expf(s0[r] + lds_emb[tok]);
            lsum[r] += p;
            plds[(quad * 4 + r) * 32 + l15] = (bf16_t)p;
        }
#pragma unroll
        for (int r = 0; r < 4; r++) {
            int dx = xi[r] - xj1; dx = dx < 0 ? -dx : dx;
            int dy = yi[r] - yj1; dy = dy < 0 ? -dy : dy;
            int tok = (dx > 5 || dy > 5) ? 36 : dx * 6 + dy;
            float p = __expf(s1[r] + lds_emb[tok]);
            lsum[r] += p;
            plds[(quad * 4 + r) * 32 + 16 + l15] = (bf16_t)p;
        }
        bf8v ap = *(const bf8v*)(plds + l15 * 32 + quad * 8);
        o0 = mfma16(ap, vf0, o0);
        o1 = mfma16(ap, vf1, o1);
        kf0 = nkf0; kf1 = nkf1; vf0 = nvf0; vf1 = nvf1;
        // advance key coords by 32 (single wrap: 32+47 < 96)
        yj0 += 32; if (yj0 >= NYY) { yj0 -= NYY; xj0++; }
        yj1 += 32; if (yj1 >= NYY) { yj1 -= NYY; xj1++; }
    }

    float* pO_s = pO + ((size_t)sidx * HH + h) * NN * HD;
    float* pl_s = pl + ((size_t)sidx * HH + h) * NN;
#pragma unroll
    for (int r = 0; r < 4; r++) {
        float v = lsum[r];
#pragma unroll
        for (int m = 1; m < 16; m <<= 1) v += __shfl_xor(v, m, 64);
        int row = qg0 + quad * 4 + r;
        pO_s[(size_t)row * HD + l15] = o0[r];
        pO_s[(size_t)row * HD + 16 + l15] = o1[r];
        if (l15 == 0) pl_s[row] = v;
    }
}

// ---------------------------------------------------------------------------
// Kernel 4: combine split-K partials -> Yt (N x 256) bf16, normalized.
// float4 loads, bf16x4 stores; grid 576 x 256 threads.
// ---------------------------------------------------------------------------
__global__ __launch_bounds__(256) void k_reduce(
    const float* __restrict__ pO, const float* __restrict__ pl,
    bf16_t* __restrict__ Yt, int S) {
    const int e4 = blockIdx.x * 256 + threadIdx.x;
    const int h = e4 / (NN * HD / 4);
    const int rem = e4 - h * (NN * HD / 4);
    const int q = rem >> 3;
    const int d = (rem & 7) * 4;
    float4 so = {0.f, 0.f, 0.f, 0.f};
    float sl = 0.f;
    for (int s = 0; s < S; s++) {
        const float4 v = *(const float4*)(pO + ((size_t)s * HH + h) * NN * HD + (size_t)q * HD + d);
        so.x += v.x; so.y += v.y; so.z += v.z; so.w += v.w;
        sl += pl[((size_t)s * HH + h) * NN + q];
    }
    const float inv = 1.0f / sl;
    bf4v o;
    o[0] = (bf16_t)(so.x * inv); o[1] = (bf16_t)(so.y * inv);
    o[2] = (bf16_t)(so.z * inv); o[3] = (bf16_t)(so.w * inv);
    *(bf4v*)(Yt + (size_t)q * CC + h * HD + d) = o;
}

// ---------------------------------------------------------------------------
// Kernel 5: output projection with in-block split-K.
// 512 threads = 8 waves: og = wave&3 (o-subtile), kg = wave>>2 (K half).
// Grid (72,4) = 288 blocks x 8 waves = 9 waves/CU (was 4.5).
// ---------------------------------------------------------------------------
__global__ __launch_bounds__(512) void k_proj_out(
    const bf16_t* __restrict__ Wb, const float* __restrict__ bp,
    const bf16_t* __restrict__ Yt, float* __restrict__ out) {
    __shared__ float red[4 * 16 * 32];
    const bf16_t* W = Wb + (size_t)3 * 65536;
    const int n0 = blockIdx.x * 32;
    const int o0 = blockIdx.y * 64;
    const int t = threadIdx.x;
    const int lane = t & 63;
    const int wave = t >> 6;
    const int og = wave & 3;
    const int kg = wave >> 2;
    const int l15 = lane & 15;
    const int quad = lane >> 4;
    const int orow = o0 + og * 16;

    f4v acc0 = {0.f, 0.f, 0.f, 0.f}, acc1 = {0.f, 0.f, 0.f, 0.f};
#pragma unroll
    for (int ki = 0; ki < 4; ki++) {
        const int k0 = kg * 128 + ki * 32;
        bf8v af = *(const bf8v*)(W + (size_t)(orow + l15) * CC + k0 + quad * 8);
        bf8v b0 = *(const bf8v*)(Yt + (size_t)(n0 + l15) * CC + k0 + quad * 8);
        bf8v b1 = *(const bf8v*)(Yt + (size_t)(n0 + 16 + l15) * CC + k0 + quad * 8);
        acc0 = mfma16(af, b0, acc0);
        acc1 = mfma16(af, b1, acc1);
    }

    float* rg = red + og * 512;
    if (kg == 1) {
#pragma unroll
        for (int r = 0; r < 4; r++) {
            rg[(quad * 4 + r) * 32 + l15] = acc0[r];
            rg[(quad * 4 + r) * 32 + 16 + l15] = acc1[r];
        }
    }
    __syncthreads();
    if (kg == 0) {
#pragma unroll
        for (int r = 0; r < 4; r++) {
            const int o = orow + quad * 4 + r;
            const float bo = bp[o];
            out[(size_t)o * NN + n0 + l15] =
                acc0[r] + rg[(quad * 4 + r) * 32 + l15] + bo;
            out[(size_t)o * NN + n0 + 16 + l15] =
                acc1[r] + rg[(quad * 4 + r) * 32 + 16 + l15] + bo;
        }
    }
}

// ---------------------------------------------------------------------------
extern "C" void kernel_launch(void* const* d_in, const int* in_sizes, int n_in,
                              void* d_out, int out_size, void* d_ws, size_t ws_size,
                              hipStream_t stream) {
    const float* x   = (const float*)d_in[0];
    const float* Wq  = (const float*)d_in[1];
    const float* bq  = (const float*)d_in[2];
    const float* Wk  = (const float*)d_in[3];
    const float* bk  = (const float*)d_in[4];
    const float* Wv  = (const float*)d_in[5];
    const float* bv  = (const float*)d_in[6];
    const float* Wp  = (const float*)d_in[7];
    const float* bp  = (const float*)d_in[8];
    const float* emb = (const float*)d_in[9];
    // d_in[10] = tokens: recomputed analytically in-kernel, never read.
    float* out = (float*)d_out;

    bf16_t* xT = (bf16_t*)d_ws;              // NN*CC bf16
    bf16_t* Qt = xT + (size_t)NN * CC;       // (H, N, 32)
    bf16_t* Kt = Qt + (size_t)NN * CC;       // (H, N, 32)
    bf16_t* Vd = Kt + (size_t)NN * CC;       // (H, 32, N)
    bf16_t* Yt = Vd + (size_t)NN * CC;       // (N, 256)
    bf16_t* Wb = Yt + (size_t)NN * CC;       // 4 * 256*256 bf16
    float*  pO = (float*)(Wb + (size_t)4 * CC * CC);  // S * H * N * 32 fp32

    const size_t base_bytes = (size_t)5 * NN * CC * 2 + (size_t)4 * CC * CC * 2;
    const size_t per_split = (size_t)HH * NN * HD * 4 + (size_t)HH * NN * 4;
    int S = 1;
    if (base_bytes + 8 * per_split <= ws_size) S = 8;
    else if (base_bytes + 4 * per_split <= ws_size) S = 4;
    else if (base_bytes + 2 * per_split <= ws_size) S = 2;
    float* pl = pO + (size_t)S * HH * NN * HD;

    hipLaunchKernelGGL(k_pre, dim3(288 + 128), dim3(256), 0, stream,
                       x, xT, Wq, Wk, Wv, Wp, Wb);
    hipLaunchKernelGGL(k_proj_qkv, dim3(72, 4, 3), dim3(256), 0, stream,
                       Wb, bq, bk, bv, xT, Qt, Kt, Vd);
    switch (S) {
        case 8: hipLaunchKernelGGL((k_attn_split<9>),  dim3(288, 8), dim3(256), 0, stream, Qt, Kt, Vd, emb, pO, pl); break;
        case 4: hipLaunchKernelGGL((k_attn_split<18>), dim3(288, 4), dim3(256), 0, stream, Qt, Kt, Vd, emb, pO, pl); break;
        case 2: hipLaunchKernelGGL((k_attn_split<36>), dim3(288, 2), dim3(256), 0, stream, Qt, Kt, Vd, emb, pO, pl); break;
        default: hipLaunchKernelGGL((k_attn_split<72>), dim3(288, 1), dim3(256), 0, stream, Qt, Kt, Vd, emb, pO, pl); break;
    }
    hipLaunchKernelGGL(k_reduce, dim3((HH * NN * HD) / 1024), dim3(256), 0, stream,
                       pO, pl, Yt, S);
    hipLaunchKernelGGL(k_proj_out, dim3(72, 4), dim3(512), 0, stream, Wb, bp, Yt, out);
}